// Round 2
// baseline (1129.043 us; speedup 1.0000x reference)
//
#include <hip/hip_runtime.h>

#define TH  0.3f
#define DEC 0.2f

// LDS layout (float offsets) — all 16B-aligned where vector-accessed
#define OFF_X    0        // 38*38 = 1444 (x, zero-padded border)
#define OFF_W1   1444     // 10*28 = 280  (repack: [oc][k*9+j], pad to 28)
#define OFF_B1   1724     // 30
#define OFF_W2   1756     // 100*28 = 2800 (repack: [oc][ic][k*9+j], pad 28)
#define OFF_B2   4556     // 30
#define OFF_LIF  4588     // 4
#define OFF_S    4592     // 10*20*20 = 4000 (pooled L1 spikes, padded border); h1 in epilogue
#define SMEM_N   8592     // 34,368 bytes

__device__ __forceinline__ float spikef(float v) { return v > TH ? 1.f : 0.f; }

// ---- layer 2: one output cell (9x9 grid), state in registers ----
__device__ __forceinline__ void layer2_cell(const float* __restrict__ sm, int cell,
                                            float lw0, float lw1, float lw2, float lb,
                                            float4* st, float* h1acc)
{
    int oc  = cell / 81;
    int rem = cell - oc * 81;
    int hh  = rem / 9;
    int ww  = rem - hh * 9;
    int y0 = 2 * hh, x0 = 2 * ww;

    float acc[4][3];
    {
        float b20 = 4.f * sm[OFF_B2 + oc];
        float b21 = 4.f * sm[OFF_B2 + 10 + oc];
        float b22 = 4.f * sm[OFF_B2 + 20 + oc];
        #pragma unroll
        for (int p = 0; p < 4; ++p) { acc[p][0] = b20; acc[p][1] = b21; acc[p][2] = b22; }
    }

    const int sb = OFF_S + y0 * 20 + x0;          // even -> float2 aligned
    const int wb = OFF_W2 + (oc * 10) * 28;       // mod 4 == 0 -> float4 aligned

    for (int ic = 0; ic < 10; ++ic) {
        float sv[4][4];
        #pragma unroll
        for (int r = 0; r < 4; ++r) {
            float2 a = *reinterpret_cast<const float2*>(&sm[sb + ic * 400 + r * 20]);
            float2 b = *reinterpret_cast<const float2*>(&sm[sb + ic * 400 + r * 20 + 2]);
            sv[r][0] = a.x; sv[r][1] = a.y; sv[r][2] = b.x; sv[r][3] = b.y;
        }
        float wv[28];
        #pragma unroll
        for (int q = 0; q < 7; ++q) {
            float4 w4 = *reinterpret_cast<const float4*>(&sm[wb + ic * 28 + q * 4]);
            wv[q * 4 + 0] = w4.x; wv[q * 4 + 1] = w4.y; wv[q * 4 + 2] = w4.z; wv[q * 4 + 3] = w4.w;
        }
        #pragma unroll
        for (int k = 0; k < 3; ++k)
            #pragma unroll
            for (int r = 0; r < 3; ++r)
                #pragma unroll
                for (int c = 0; c < 3; ++c) {
                    float wvv = wv[k * 9 + r * 3 + c];
                    acc[0][k] = fmaf(sv[r][c],         wvv, acc[0][k]);
                    acc[1][k] = fmaf(sv[r][c + 1],     wvv, acc[1][k]);
                    acc[2][k] = fmaf(sv[r + 1][c],     wvv, acc[2][k]);
                    acc[3][k] = fmaf(sv[r + 1][c + 1], wvv, acc[3][k]);
                }
    }

    #pragma unroll
    for (int p = 0; p < 4; ++p) {
        float4 m = st[p];
        float inner = fmaf(m.x, lw0, fmaf(m.y, lw1, fmaf(m.z, lw2, lb)));
        float4 n;
        n.x = (m.x > TH ? 0.f : m.x * DEC) + acc[p][0];
        n.y = (m.y > TH ? 0.f : m.y * DEC) + acc[p][1];
        n.z = (m.z > TH ? 0.f : m.z * DEC) + acc[p][2];
        n.w = (m.w > TH ? 0.f : m.w * DEC) + inner;
        st[p] = n;
        h1acc[0] += spikef(n.x) * 0.25f;
        h1acc[1] += spikef(n.y) * 0.25f;
        h1acc[2] += spikef(n.z) * 0.25f;
        h1acc[3] += spikef(n.w) * 0.25f;
    }
}

// ---- layer 1: one cell (18x18 grid), conv from LDS-x, state in registers ----
__device__ __forceinline__ void layer1_cell(float* __restrict__ sm, int cell,
                                            float lw0, float lw1, float lw2, float lb,
                                            float4* st)
{
    int oc  = cell / 324;
    int rem = cell - oc * 324;
    int hh  = rem / 18;
    int ww  = rem - hh * 18;
    int y0 = 2 * hh, x0 = 2 * ww;

    float xv[4][4];
    #pragma unroll
    for (int r = 0; r < 4; ++r) {
        float2 a = *reinterpret_cast<const float2*>(&sm[OFF_X + (y0 + r) * 38 + x0]);
        float2 b = *reinterpret_cast<const float2*>(&sm[OFF_X + (y0 + r) * 38 + x0 + 2]);
        xv[r][0] = a.x; xv[r][1] = a.y; xv[r][2] = b.x; xv[r][3] = b.y;
    }
    float wv[28];
    #pragma unroll
    for (int q = 0; q < 7; ++q) {
        float4 w4 = *reinterpret_cast<const float4*>(&sm[OFF_W1 + oc * 28 + q * 4]);
        wv[q * 4 + 0] = w4.x; wv[q * 4 + 1] = w4.y; wv[q * 4 + 2] = w4.z; wv[q * 4 + 3] = w4.w;
    }
    float d[4][3];
    {
        float b0 = sm[OFF_B1 + oc], b1v = sm[OFF_B1 + 10 + oc], b2v = sm[OFF_B1 + 20 + oc];
        #pragma unroll
        for (int p = 0; p < 4; ++p) { d[p][0] = b0; d[p][1] = b1v; d[p][2] = b2v; }
    }
    #pragma unroll
    for (int k = 0; k < 3; ++k)
        #pragma unroll
        for (int r = 0; r < 3; ++r)
            #pragma unroll
            for (int c = 0; c < 3; ++c) {
                float wvv = wv[k * 9 + r * 3 + c];
                d[0][k] = fmaf(xv[r][c],         wvv, d[0][k]);
                d[1][k] = fmaf(xv[r][c + 1],     wvv, d[1][k]);
                d[2][k] = fmaf(xv[r + 1][c],     wvv, d[2][k]);
                d[3][k] = fmaf(xv[r + 1][c + 1], wvv, d[3][k]);
            }

    float ssum = 0.f;
    #pragma unroll
    for (int p = 0; p < 4; ++p) {
        float4 m = st[p];
        float inner = fmaf(m.x, lw0, fmaf(m.y, lw1, fmaf(m.z, lw2, lb)));
        float4 n;
        n.x = (m.x > TH ? 0.f : m.x * DEC) + d[p][0];
        n.y = (m.y > TH ? 0.f : m.y * DEC) + d[p][1];
        n.z = (m.z > TH ? 0.f : m.z * DEC) + d[p][2];
        n.w = (m.w > TH ? 0.f : m.w * DEC) + inner;
        st[p] = n;
        ssum += spikef(n.x) + spikef(n.y) + spikef(n.z) + spikef(n.w);
    }
    sm[OFF_S + oc * 400 + (hh + 1) * 20 + (ww + 1)] = ssum * 0.25f;
}

__global__ __launch_bounds__(512, 2)
void scnn_kernel(const float* __restrict__ x,
                 const float* __restrict__ w1, const float* __restrict__ b1,
                 const float* __restrict__ w2, const float* __restrict__ b2,
                 const float* __restrict__ lif_w, const float* __restrict__ lif_b,
                 const float* __restrict__ fc_w, const float* __restrict__ fc_b,
                 const float* __restrict__ task_w, const float* __restrict__ task_b,
                 const int* __restrict__ tw_ptr,
                 float* __restrict__ out)
{
    __shared__ float sm[SMEM_N];
    const int tid = threadIdx.x;
    const int b   = blockIdx.x;
    const int T   = tw_ptr[0];

    for (int i = tid; i < SMEM_N; i += 512) sm[i] = 0.f;
    __syncthreads();

    for (int i = tid; i < 1296; i += 512) {
        int h = i / 36, w = i - h * 36;
        sm[OFF_X + (h + 1) * 38 + (w + 1)] = x[b * 1296 + i];
    }
    if (tid < 270) { // w1 (3,10,1,3,3) -> [oc][k*9+j] pad 28
        int k = tid / 90, r = tid - k * 90;
        int oc = r / 9, j = r - oc * 9;
        sm[OFF_W1 + oc * 28 + k * 9 + j] = w1[tid];
    }
    if (tid < 30)  sm[OFF_B1 + tid] = b1[tid];
    for (int i = tid; i < 2700; i += 512) { // w2 (3,10,10,3,3) -> [oc][ic][k*9+j] pad 28
        int k = i / 900, r1 = i - k * 900;
        int oc = r1 / 90, r2 = r1 - oc * 90;
        int ic = r2 / 9,  j  = r2 - ic * 9;
        sm[OFF_W2 + (oc * 10 + ic) * 28 + k * 9 + j] = w2[i];
    }
    if (tid < 30)  sm[OFF_B2 + tid] = b2[tid];
    if (tid < 3)   sm[OFF_LIF + tid] = lif_w[tid];
    if (tid == 0)  sm[OFF_LIF + 3] = lif_b[0];
    __syncthreads();

    const float lw0 = sm[OFF_LIF + 0], lw1 = sm[OFF_LIF + 1],
                lw2 = sm[OFF_LIF + 2], lb  = sm[OFF_LIF + 3];

    // all recurrent state in registers
    float4 m1[7][4];   // layer-1 mem: cells tid + i*512, [pix] x (k0..k3)
    float4 m2a[4], m2b[4];
    #pragma unroll
    for (int i = 0; i < 7; ++i)
        #pragma unroll
        for (int p = 0; p < 4; ++p) m1[i][p] = make_float4(0.f, 0.f, 0.f, 0.f);
    #pragma unroll
    for (int p = 0; p < 4; ++p) { m2a[p] = make_float4(0.f,0.f,0.f,0.f); m2b[p] = make_float4(0.f,0.f,0.f,0.f); }

    float h1a[4] = {0.f,0.f,0.f,0.f};
    float h1b[4] = {0.f,0.f,0.f,0.f};

    for (int t = 0; t < T; ++t) {
        #pragma unroll
        for (int i = 0; i < 6; ++i)
            layer1_cell(sm, tid + i * 512, lw0, lw1, lw2, lb, m1[i]);
        if (tid < 3240 - 6 * 512)
            layer1_cell(sm, tid + 6 * 512, lw0, lw1, lw2, lb, m1[6]);
        __syncthreads();

        layer2_cell(sm, tid, lw0, lw1, lw2, lb, m2a, h1a);
        if (tid < 810 - 512)
            layer2_cell(sm, tid + 512, lw0, lw1, lw2, lb, m2b, h1b);
        __syncthreads();
    }

    // ---- epilogue: h1 -> LDS (overwrites s region), FC(50x3240), task heads ----
    *reinterpret_cast<float4*>(&sm[OFF_S + tid * 4]) = make_float4(h1a[0], h1a[1], h1a[2], h1a[3]);
    if (tid < 810 - 512)
        *reinterpret_cast<float4*>(&sm[OFF_S + (tid + 512) * 4]) = make_float4(h1b[0], h1b[1], h1b[2], h1b[3]);
    __syncthreads();

    float invT = 1.f / (float)T;
    int f = tid >> 3, g = tid & 7;
    if (f < 50) {
        const float* wrow = fc_w + f * 3240;
        float p0 = 0.f, p1 = 0.f;
        for (int j = g; j < 3240; j += 16) {
            p0 = fmaf(sm[OFF_S + j], wrow[j], p0);
            if (j + 8 < 3240) p1 = fmaf(sm[OFF_S + j + 8], wrow[j + 8], p1);
        }
        float p = p0 + p1;
        p += __shfl_xor(p, 1);
        p += __shfl_xor(p, 2);
        p += __shfl_xor(p, 4);
        if (g == 0) sm[OFF_X + f] = p * invT + fc_b[f];
    }
    __syncthreads();

    if (tid < 30) {
        float acc = task_b[tid];
        const float* twp = task_w + tid * 50;
        for (int j = 0; j < 50; ++j) acc = fmaf(sm[OFF_X + j], twp[j], acc);
        out[b * 30 + tid] = acc;
    }
}

extern "C" void kernel_launch(void* const* d_in, const int* in_sizes, int n_in,
                              void* d_out, int out_size, void* d_ws, size_t ws_size,
                              hipStream_t stream) {
    const float* x      = (const float*)d_in[0];
    const float* w1     = (const float*)d_in[1];
    const float* b1     = (const float*)d_in[2];
    const float* w2     = (const float*)d_in[3];
    const float* b2     = (const float*)d_in[4];
    const float* lif_w  = (const float*)d_in[5];
    const float* lif_b  = (const float*)d_in[6];
    const float* fc_w   = (const float*)d_in[7];
    const float* fc_b   = (const float*)d_in[8];
    const float* task_w = (const float*)d_in[9];
    const float* task_b = (const float*)d_in[10];
    const int*   tw     = (const int*)d_in[11];

    int B = in_sizes[0] / 1296;  // x is (B,1,36,36)

    scnn_kernel<<<B, 512, 0, stream>>>(x, w1, b1, w2, b2, lif_w, lif_b,
                                       fc_w, fc_b, task_w, task_b, tw,
                                       (float*)d_out);
}

// Round 3
// 1106.978 us; speedup vs baseline: 1.0199x; 1.0199x over previous
//
#include <hip/hip_runtime.h>

#define TH  0.3f
#define DEC 0.2f

// LDS layout (float offsets) — all 16B-aligned where vector-accessed
#define OFF_X    0        // 38*38 = 1444 (x, zero-padded border)
#define OFF_W1   1444     // 10*28 = 280  (repack: [oc][k*9+j], pad to 28)
#define OFF_B1   1724     // 30
#define OFF_W2   1756     // 100*28 = 2800 (repack: [oc][ic][k*9+j], pad 28)
#define OFF_B2   4556     // 30
#define OFF_LIF  4588     // 4
#define OFF_S    4592     // 10*20*20 = 4000 (pooled L1 spikes, padded border); h1 in epilogue
#define SMEM_N   8592     // 34,368 bytes

__device__ __forceinline__ float spikef(float v) { return v > TH ? 1.f : 0.f; }

// ---- layer 2: one output cell (9x9 grid), state in registers ----
__device__ __forceinline__ void layer2_cell(const float* __restrict__ sm, int cell,
                                            float lw0, float lw1, float lw2, float lb,
                                            float4* st, float* h1acc)
{
    int oc  = cell / 81;
    int rem = cell - oc * 81;
    int hh  = rem / 9;
    int ww  = rem - hh * 9;
    int y0 = 2 * hh, x0 = 2 * ww;

    float acc[4][3];
    {
        float b20 = 4.f * sm[OFF_B2 + oc];
        float b21 = 4.f * sm[OFF_B2 + 10 + oc];
        float b22 = 4.f * sm[OFF_B2 + 20 + oc];
        #pragma unroll
        for (int p = 0; p < 4; ++p) { acc[p][0] = b20; acc[p][1] = b21; acc[p][2] = b22; }
    }

    const int sb = OFF_S + y0 * 20 + x0;          // even -> float2 aligned
    const int wb = OFF_W2 + (oc * 10) * 28;       // mod 4 == 0 -> float4 aligned

    for (int ic = 0; ic < 10; ++ic) {
        float sv[4][4];
        #pragma unroll
        for (int r = 0; r < 4; ++r) {
            float2 a = *reinterpret_cast<const float2*>(&sm[sb + ic * 400 + r * 20]);
            float2 b = *reinterpret_cast<const float2*>(&sm[sb + ic * 400 + r * 20 + 2]);
            sv[r][0] = a.x; sv[r][1] = a.y; sv[r][2] = b.x; sv[r][3] = b.y;
        }
        float wv[28];
        #pragma unroll
        for (int q = 0; q < 7; ++q) {
            float4 w4 = *reinterpret_cast<const float4*>(&sm[wb + ic * 28 + q * 4]);
            wv[q * 4 + 0] = w4.x; wv[q * 4 + 1] = w4.y; wv[q * 4 + 2] = w4.z; wv[q * 4 + 3] = w4.w;
        }
        #pragma unroll
        for (int k = 0; k < 3; ++k)
            #pragma unroll
            for (int r = 0; r < 3; ++r)
                #pragma unroll
                for (int c = 0; c < 3; ++c) {
                    float wvv = wv[k * 9 + r * 3 + c];
                    acc[0][k] = fmaf(sv[r][c],         wvv, acc[0][k]);
                    acc[1][k] = fmaf(sv[r][c + 1],     wvv, acc[1][k]);
                    acc[2][k] = fmaf(sv[r + 1][c],     wvv, acc[2][k]);
                    acc[3][k] = fmaf(sv[r + 1][c + 1], wvv, acc[3][k]);
                }
    }

    #pragma unroll
    for (int p = 0; p < 4; ++p) {
        float4 m = st[p];
        float inner = fmaf(m.x, lw0, fmaf(m.y, lw1, fmaf(m.z, lw2, lb)));
        float4 n;
        n.x = (m.x > TH ? 0.f : m.x * DEC) + acc[p][0];
        n.y = (m.y > TH ? 0.f : m.y * DEC) + acc[p][1];
        n.z = (m.z > TH ? 0.f : m.z * DEC) + acc[p][2];
        n.w = (m.w > TH ? 0.f : m.w * DEC) + inner;
        st[p] = n;
        h1acc[0] += spikef(n.x) * 0.25f;
        h1acc[1] += spikef(n.y) * 0.25f;
        h1acc[2] += spikef(n.z) * 0.25f;
        h1acc[3] += spikef(n.w) * 0.25f;
    }
}

// ---- layer 1: one cell (18x18 grid), conv from LDS-x, state in registers ----
__device__ __forceinline__ void layer1_cell(float* __restrict__ sm, int cell,
                                            float lw0, float lw1, float lw2, float lb,
                                            float4* st)
{
    int oc  = cell / 324;
    int rem = cell - oc * 324;
    int hh  = rem / 18;
    int ww  = rem - hh * 18;
    int y0 = 2 * hh, x0 = 2 * ww;

    float xv[4][4];
    #pragma unroll
    for (int r = 0; r < 4; ++r) {
        float2 a = *reinterpret_cast<const float2*>(&sm[OFF_X + (y0 + r) * 38 + x0]);
        float2 b = *reinterpret_cast<const float2*>(&sm[OFF_X + (y0 + r) * 38 + x0 + 2]);
        xv[r][0] = a.x; xv[r][1] = a.y; xv[r][2] = b.x; xv[r][3] = b.y;
    }
    float wv[28];
    #pragma unroll
    for (int q = 0; q < 7; ++q) {
        float4 w4 = *reinterpret_cast<const float4*>(&sm[OFF_W1 + oc * 28 + q * 4]);
        wv[q * 4 + 0] = w4.x; wv[q * 4 + 1] = w4.y; wv[q * 4 + 2] = w4.z; wv[q * 4 + 3] = w4.w;
    }
    float d[4][3];
    {
        float b0 = sm[OFF_B1 + oc], b1v = sm[OFF_B1 + 10 + oc], b2v = sm[OFF_B1 + 20 + oc];
        #pragma unroll
        for (int p = 0; p < 4; ++p) { d[p][0] = b0; d[p][1] = b1v; d[p][2] = b2v; }
    }
    #pragma unroll
    for (int k = 0; k < 3; ++k)
        #pragma unroll
        for (int r = 0; r < 3; ++r)
            #pragma unroll
            for (int c = 0; c < 3; ++c) {
                float wvv = wv[k * 9 + r * 3 + c];
                d[0][k] = fmaf(xv[r][c],         wvv, d[0][k]);
                d[1][k] = fmaf(xv[r][c + 1],     wvv, d[1][k]);
                d[2][k] = fmaf(xv[r + 1][c],     wvv, d[2][k]);
                d[3][k] = fmaf(xv[r + 1][c + 1], wvv, d[3][k]);
            }

    float ssum = 0.f;
    #pragma unroll
    for (int p = 0; p < 4; ++p) {
        float4 m = st[p];
        float inner = fmaf(m.x, lw0, fmaf(m.y, lw1, fmaf(m.z, lw2, lb)));
        float4 n;
        n.x = (m.x > TH ? 0.f : m.x * DEC) + d[p][0];
        n.y = (m.y > TH ? 0.f : m.y * DEC) + d[p][1];
        n.z = (m.z > TH ? 0.f : m.z * DEC) + d[p][2];
        n.w = (m.w > TH ? 0.f : m.w * DEC) + inner;
        st[p] = n;
        ssum += spikef(n.x) + spikef(n.y) + spikef(n.z) + spikef(n.w);
    }
    sm[OFF_S + oc * 400 + (hh + 1) * 20 + (ww + 1)] = ssum * 0.25f;
}

__global__ __launch_bounds__(512, 2)
void scnn_kernel(const float* __restrict__ x,
                 const float* __restrict__ w1, const float* __restrict__ b1,
                 const float* __restrict__ w2, const float* __restrict__ b2,
                 const float* __restrict__ lif_w, const float* __restrict__ lif_b,
                 const float* __restrict__ fc_w, const float* __restrict__ fc_b,
                 const float* __restrict__ task_w, const float* __restrict__ task_b,
                 const int* __restrict__ tw_ptr,
                 float* __restrict__ out)
{
    __shared__ float sm[SMEM_N];
    const int tid = threadIdx.x;
    const int b   = blockIdx.x;
    const int T   = tw_ptr[0];

    for (int i = tid; i < SMEM_N; i += 512) sm[i] = 0.f;
    __syncthreads();

    for (int i = tid; i < 1296; i += 512) {
        int h = i / 36, w = i - h * 36;
        sm[OFF_X + (h + 1) * 38 + (w + 1)] = x[b * 1296 + i];
    }
    if (tid < 270) { // w1 (3,10,1,3,3) -> [oc][k*9+j] pad 28
        int k = tid / 90, r = tid - k * 90;
        int oc = r / 9, j = r - oc * 9;
        sm[OFF_W1 + oc * 28 + k * 9 + j] = w1[tid];
    }
    if (tid < 30)  sm[OFF_B1 + tid] = b1[tid];
    for (int i = tid; i < 2700; i += 512) { // w2 (3,10,10,3,3) -> [oc][ic][k*9+j] pad 28
        int k = i / 900, r1 = i - k * 900;
        int oc = r1 / 90, r2 = r1 - oc * 90;
        int ic = r2 / 9,  j  = r2 - ic * 9;
        sm[OFF_W2 + (oc * 10 + ic) * 28 + k * 9 + j] = w2[i];
    }
    if (tid < 30)  sm[OFF_B2 + tid] = b2[tid];
    if (tid < 3)   sm[OFF_LIF + tid] = lif_w[tid];
    if (tid == 0)  sm[OFF_LIF + 3] = lif_b[0];
    __syncthreads();

    const float lw0 = sm[OFF_LIF + 0], lw1 = sm[OFF_LIF + 1],
                lw2 = sm[OFF_LIF + 2], lb  = sm[OFF_LIF + 3];

    // all recurrent state in registers
    float4 m1[7][4];   // layer-1 mem: cells tid + i*512, [pix] x (k0..k3)
    float4 m2a[4], m2b[4];
    #pragma unroll
    for (int i = 0; i < 7; ++i)
        #pragma unroll
        for (int p = 0; p < 4; ++p) m1[i][p] = make_float4(0.f, 0.f, 0.f, 0.f);
    #pragma unroll
    for (int p = 0; p < 4; ++p) { m2a[p] = make_float4(0.f,0.f,0.f,0.f); m2b[p] = make_float4(0.f,0.f,0.f,0.f); }

    float h1a[4] = {0.f,0.f,0.f,0.f};
    float h1b[4] = {0.f,0.f,0.f,0.f};

    for (int t = 0; t < T; ++t) {
        #pragma unroll
        for (int i = 0; i < 6; ++i)
            layer1_cell(sm, tid + i * 512, lw0, lw1, lw2, lb, m1[i]);
        if (tid < 3240 - 6 * 512)
            layer1_cell(sm, tid + 6 * 512, lw0, lw1, lw2, lb, m1[6]);
        __syncthreads();

        layer2_cell(sm, tid, lw0, lw1, lw2, lb, m2a, h1a);
        if (tid < 810 - 512)
            layer2_cell(sm, tid + 512, lw0, lw1, lw2, lb, m2b, h1b);
        __syncthreads();
    }

    // ---- epilogue: h1 -> LDS (overwrites s region), FC(50x3240), task heads ----
    *reinterpret_cast<float4*>(&sm[OFF_S + tid * 4]) = make_float4(h1a[0], h1a[1], h1a[2], h1a[3]);
    if (tid < 810 - 512)
        *reinterpret_cast<float4*>(&sm[OFF_S + (tid + 512) * 4]) = make_float4(h1b[0], h1b[1], h1b[2], h1b[3]);
    __syncthreads();

    float invT = 1.f / (float)T;
    int f = tid >> 3, g = tid & 7;
    if (f < 50) {
        const float* wrow = fc_w + f * 3240;
        float p0 = 0.f, p1 = 0.f;
        for (int j = g; j < 3240; j += 16) {
            p0 = fmaf(sm[OFF_S + j], wrow[j], p0);
            if (j + 8 < 3240) p1 = fmaf(sm[OFF_S + j + 8], wrow[j + 8], p1);
        }
        float p = p0 + p1;
        p += __shfl_xor(p, 1);
        p += __shfl_xor(p, 2);
        p += __shfl_xor(p, 4);
        if (g == 0) sm[OFF_X + f] = p * invT + fc_b[f];
    }
    __syncthreads();

    if (tid < 30) {
        float acc = task_b[tid];
        const float* twp = task_w + tid * 50;
        for (int j = 0; j < 50; ++j) acc = fmaf(sm[OFF_X + j], twp[j], acc);
        out[b * 30 + tid] = acc;
    }
}

extern "C" void kernel_launch(void* const* d_in, const int* in_sizes, int n_in,
                              void* d_out, int out_size, void* d_ws, size_t ws_size,
                              hipStream_t stream) {
    const float* x      = (const float*)d_in[0];
    const float* w1     = (const float*)d_in[1];
    const float* b1     = (const float*)d_in[2];
    const float* w2     = (const float*)d_in[3];
    const float* b2     = (const float*)d_in[4];
    const float* lif_w  = (const float*)d_in[5];
    const float* lif_b  = (const float*)d_in[6];
    const float* fc_w   = (const float*)d_in[7];
    const float* fc_b   = (const float*)d_in[8];
    const float* task_w = (const float*)d_in[9];
    const float* task_b = (const float*)d_in[10];
    const int*   tw     = (const int*)d_in[11];

    int B = in_sizes[0] / 1296;  // x is (B,1,36,36)

    scnn_kernel<<<B, 512, 0, stream>>>(x, w1, b1, w2, b2, lif_w, lif_b,
                                       fc_w, fc_b, task_w, task_b, tw,
                                       (float*)d_out);
}